// Round 16
// baseline (176.195 us; speedup 1.0000x reference)
//
#include <hip/hip_runtime.h>
#include <cstdint>

#define Bb 4
#define Lseq 4096
#define Hh 1024
#define Nst 64
constexpr float LN_EPS = 1e-5f;

typedef _Float16 f16x8 __attribute__((ext_vector_type(8)));
typedef _Float16 f16x4 __attribute__((ext_vector_type(4)));
typedef float f32x4v __attribute__((ext_vector_type(4)));

// XOR-swizzle within a 64x64 f16 matrix: elem e=(row*64+col) stored at
// e ^ ((row&7)<<3). ALL matrices (U, M1, P) are generated in-kernel in
// k_chunk directly at swizzled LDS offsets — no global mats buffer at all.
__device__ __forceinline__ void cmul(float& zR, float& zI, float bR, float bI) {
    const float tR = fmaf(zR, bR, -zI * bI);
    zI = fmaf(zR, bI, zI * bR);
    zR = tR;
}

// ---------------------------------------------------------------------------
// K0+K1 fused: precompute (blocks 0..1023) overlaps transpose (blocks 1024+).
// Precompute emits ONLY small tables: w1 = exp(dA), w64 (scan weight),
// Ct (cR/cI), K[0..63] per h.
// ---------------------------------------------------------------------------
__global__ __launch_bounds__(256) void k_pre_trans(
    const float* __restrict__ x, _Float16* __restrict__ xt,
    const float* __restrict__ logA, const float* __restrict__ Aim,
    const float* __restrict__ Cre, const float* __restrict__ Cim,
    const float* __restrict__ logdt,
    float* __restrict__ wwR, float* __restrict__ wwI,
    float* __restrict__ w1R, float* __restrict__ w1I,
    float* __restrict__ cRt, float* __restrict__ cIt,
    float* __restrict__ ktab) {
    __shared__ float tile[64 * 65];               // transpose path (16.6KB)
    __shared__ float sdAr[64], sdAi[64], scR[64], scI[64];
    const int tid = threadIdx.x;

    if (blockIdx.x < Hh) {
        // ---------------- precompute path (tables only) ----------------
        const int h = blockIdx.x;

        if (tid < 64) {
            const int n = tid, idx = h * 64 + n;
            const float ar = -__expf(logA[idx]), ai = Aim[idx];
            const float dt = __expf(logdt[h]);
            const float dAr = dt * ar, dAi = dt * ai;
            const float em = __expf(dAr);
            const float wr = em * __cosf(dAi), wi = em * __sinf(dAi);
            const float Er = wr - 1.0f, Ei = wi;
            const float cr = Cre[idx], ci = Cim[idx];
            const float nr = cr * Er - ci * Ei, ni = cr * Ei + ci * Er;
            const float invd = 1.0f / (ar * ar + ai * ai);
            const float CtR = (nr * ar + ni * ai) * invd;
            const float CtI = (ni * ar - nr * ai) * invd;
            sdAr[n] = dAr; sdAi[n] = dAi;
            scR[n] = 2.0f * CtR; scI[n] = 2.0f * CtI;
            w1R[idx] = wr;  w1I[idx] = wi;        // w = exp(dA)
            cRt[idx] = 2.0f * CtR; cIt[idx] = 2.0f * CtI;
            const float e64 = __expf(dAr * 64.0f), a64 = dAi * 64.0f;
            wwR[idx] = e64 * __cosf(a64);         // w^64 (scan weight)
            wwI[idx] = e64 * __sinf(a64);
        }
        __syncthreads();

        // K[tau] -> global ktab: tau = tid>>2, each of 4 lanes sums 16 n's,
        // then shfl_xor(1,2) reduce within the aligned 4-lane group.
        {
            const int tau = tid >> 2, ns0 = (tid & 3) * 16;
            const float ftau = (float)tau;
            float sum = 0.0f;
#pragma unroll
            for (int j = 0; j < 16; ++j) {
                const int n = ns0 + j;
                const float ee = __expf(sdAr[n] * ftau), ang = sdAi[n] * ftau;
                sum += ee * (scR[n] * __cosf(ang) - scI[n] * __sinf(ang));
            }
            sum += __shfl_xor(sum, 1);
            sum += __shfl_xor(sum, 2);
            if ((tid & 3) == 0) ktab[h * 64 + tau] = sum;
        }
    } else {
        // ---------------- transpose path (f32 in, f16 out) ----------------
        const int tb = blockIdx.x - Hh;
        const int h0 = (tb & 15) * 64;
        const int l0 = ((tb >> 4) & 63) * 64;
        const int b  = tb >> 10;
        const int c = tid & 15, r = tid >> 4;

        const float* src = x + ((size_t)(b * Lseq + l0 + r)) * Hh + h0 + 4 * c;
#pragma unroll
        for (int it = 0; it < 4; ++it) {
            const float4 v = *(const float4*)(src + (size_t)it * 16 * Hh);
            const int l = it * 16 + r;
            tile[(4 * c + 0) * 65 + l] = v.x;
            tile[(4 * c + 1) * 65 + l] = v.y;
            tile[(4 * c + 2) * 65 + l] = v.z;
            tile[(4 * c + 3) * 65 + l] = v.w;
        }
        __syncthreads();
        // store pass: 8 l-octets x 32 h-rows -> 2x 16B f16x8 stores/thread
        const int c8 = tid & 7, r32 = tid >> 3;
        _Float16* dst = xt + ((size_t)(b * Hh + h0 + r32)) * Lseq + l0 + 8 * c8;
#pragma unroll
        for (int it = 0; it < 2; ++it) {
            const float* trow = tile + (it * 32 + r32) * 65 + 8 * c8;
            f16x8 o;
#pragma unroll
            for (int j = 0; j < 8; ++j) o[j] = (_Float16)trow[j];
            *(f16x8*)(dst + (size_t)it * 32 * Lseq) = o;
        }
    }
}

// ---------------------------------------------------------------------------
// K2: chunked block-scan via MFMA. 512 threads / 2 batches per block,
// grid (2, Hh), 3 blocks/CU (51200B LDS overlay). R15 structure; ONLY
// change: the scan keeps all 32 u values (R+I x 16 c) in REGISTERS after
// step 1 (aR/aI are dead by then, so the 32 f32 fit the 85-reg budget) and
// step 3 becomes write-only. Scan LDS ops 96 -> 64 b16; chunk is LDS-pipe-
// bound (~230 DS wave-ops/thread ~= 11K cy/block vs 12K residency), so
// every removed DS op pays. Numerically bit-identical.
// ---------------------------------------------------------------------------
#define MR0 0        // U_re   f16 [64][64] stride 128B, XOR-swizzled (phase 1)
#define MI0 8192     // U_im   (phase 1)
#define MM1 16384    // M1     (phase 1)
#define USB 0        // u/S: 2 x { S_R [64][68], S_I [64][68] } stride 136B
                     //   overlaps U/M1 after the post-phase-1 barrier
#define MPR 34816    // P_re   (generated, disjoint)
#define MPI 43008    // P_im_neg

// row0 is a multiple of 16 at every use, so (row0+col)&7 == col&7
#define MFRAG(base, row0, kk) \
    (*(const f16x8*)(sm + (((base) + ((row0) + col) * 128 + ((kk) + qd * 8) * 2) ^ ((col & 7) << 4))))

static __device__ __forceinline__ f16x8 ufrag(const unsigned char* sm, int off) {
    union { f16x8 v; f16x4 h[2]; } u;
    u.h[0] = *(const f16x4*)(sm + off);      // 8B aligned
    u.h[1] = *(const f16x4*)(sm + off + 8);
    return u.v;
}

__global__ __launch_bounds__(512, 6) void k_chunk(
    const _Float16* __restrict__ xt, _Float16* __restrict__ rt,
    const float* __restrict__ wwR, const float* __restrict__ wwI,
    const float* __restrict__ w1R, const float* __restrict__ w1I,
    const float* __restrict__ cRt, const float* __restrict__ cIt,
    const float* __restrict__ ktab, const float* __restrict__ Dp) {
    __shared__ __align__(16) unsigned char sm[51200];

    const int tid = threadIdx.x, lane = tid & 63, wv = tid >> 6;
    const int grp = wv >> 2;          // 0..1: which batch of this block's pair
    const int wb  = wv & 3;           // row-band wave 0..3
    const int h = blockIdx.y;
    const int b = blockIdx.x * 2 + grp;   // batch 0..3
    const int col = lane & 15, qd = lane >> 4;
    const int band = wb * 16;
    const int uRo = USB + grp * 17408;
    const int uIo = uRo + 8704;

    const float Dp1 = 1.0f + Dp[h];
    const _Float16* xr = xt + ((size_t)b * Hh + h) * Lseq;

    // ---- phase-1 fragment loads (latency hides under U/M1/P gen) ----
    f16x8 axk[2];
#pragma unroll
    for (int kh2 = 0; kh2 < 2; ++kh2)
        axk[kh2] = *(const f16x8*)(xr + (band + col) * 64 + kh2 * 32 + qd * 8);

    // scan weight ww = w^64 for this lane's n = band + (lane&15); all lanes
    const float swR = wwR[h * 64 + band + (lane & 15)];
    const float swI = wwI[h * 64 + band + (lane & 15)];

    // ---- generate U (w^p geometric rows) into swizzled LDS ----
    {
        const int n = tid >> 3, oct = tid & 7;
        const float wR = w1R[h * 64 + n], wI = w1I[h * 64 + n];
        const float w2R = fmaf(wR, wR, -wI * wI),     w2I = 2.0f * wR * wI;
        const float w4R = fmaf(w2R, w2R, -w2I * w2I), w4I = 2.0f * w2R * w2I;
        const float w8R = fmaf(w4R, w4R, -w4I * w4I), w8I = 2.0f * w4R * w4I;
        const int k = 7 - oct;                        // z = (w^8)^k
        float zR = 1.0f, zI = 0.0f;
        if (k & 1) cmul(zR, zI, w8R, w8I);
        const float w16R = fmaf(w8R, w8R, -w8I * w8I), w16I = 2.0f * w8R * w8I;
        if (k & 2) cmul(zR, zI, w16R, w16I);
        const float w32R = fmaf(w16R, w16R, -w16I * w16I),
                    w32I = 2.0f * w16R * w16I;
        if (k & 4) cmul(zR, zI, w32R, w32I);
        // octet elems: v[j] = w^(63-8*oct-j); j=7 -> z, then multiply up
        f16x8 ur, ui;
        ur[7] = (_Float16)zR; ui[7] = (_Float16)zI;
#pragma unroll
        for (int j = 6; j >= 0; --j) {
            cmul(zR, zI, wR, wI);
            ur[j] = (_Float16)zR; ui[j] = (_Float16)zI;
        }
        const int sb = n * 128 + ((oct ^ (n & 7)) << 4);
        *(f16x8*)(sm + MR0 + sb) = ur;
        *(f16x8*)(sm + MI0 + sb) = ui;
    }

    // ---- generate M1 (tril Toeplitz of K) into swizzled LDS ----
    {
        const int t = tid >> 3, oct = tid & 7;
        f16x8 m1;
#pragma unroll
        for (int i = 0; i < 8; ++i) {
            const int j = oct * 8 + i;
            float v = 0.0f;
            if (j <= t) v = ktab[h * 64 + (t - j)];
            m1[i] = (_Float16)v;
        }
        const int sb = t * 128 + ((oct ^ (t & 7)) << 4);
        *(f16x8*)(sm + MM1 + sb) = m1;
    }

    // ---- generate P (Ct * w^(t+1), geometric in t) into swizzled LDS ----
    {
        const int n = tid & 63, k = tid >> 6;
        const float wR = w1R[h * 64 + n], wI = w1I[h * 64 + n];
        const float w2R = fmaf(wR, wR, -wI * wI),     w2I = 2.0f * wR * wI;
        const float w4R = fmaf(w2R, w2R, -w2I * w2I), w4I = 2.0f * w2R * w2I;
        const float w8R = fmaf(w4R, w4R, -w4I * w4I), w8I = 2.0f * w4R * w4I;
        float zR = 1.0f, zI = 0.0f;                   // w^(8k)
        if (k & 1) cmul(zR, zI, w8R, w8I);
        const float w16R = fmaf(w8R, w8R, -w8I * w8I), w16I = 2.0f * w8R * w8I;
        if (k & 2) cmul(zR, zI, w16R, w16I);
        const float w32R = fmaf(w16R, w16R, -w16I * w16I),
                    w32I = 2.0f * w16R * w16I;
        if (k & 4) cmul(zR, zI, w32R, w32I);
        float pR = cRt[h * 64 + n], pI = cIt[h * 64 + n];   // Ct
        cmul(pR, pI, zR, zI);                         // Ct * w^(8k)
        cmul(pR, pI, wR, wI);                         // Ct * w^(8k+1)
#pragma unroll
        for (int j = 0; j < 8; ++j) {
            const int t = k * 8 + j;
            const int off = t * 128 + ((n * 2) ^ (j << 4));
            *(_Float16*)(sm + MPR + off) = (_Float16)pR;
            *(_Float16*)(sm + MPI + off) = (_Float16)(-pI);
            cmul(pR, pI, wR, wI);
        }
    }
    __syncthreads();  // U/M1/P in LDS + x loads ready

    // ---- phase 1: u = X @ U^T (complex) + hoisted X@M1 ----
    f32x4v aR[4] = {}, aI[4] = {};
    f32x4v acc[4] = {};
    __builtin_amdgcn_s_setprio(1);
#pragma unroll
    for (int kh2 = 0; kh2 < 2; ++kh2) {
        const int kk = kh2 * 32;
#pragma unroll
        for (int nt = 0; nt < 4; ++nt) {
            aR[nt] = __builtin_amdgcn_mfma_f32_16x16x32_f16(
                axk[kh2], MFRAG(MR0, nt * 16, kk), aR[nt], 0, 0, 0);
            aI[nt] = __builtin_amdgcn_mfma_f32_16x16x32_f16(
                axk[kh2], MFRAG(MI0, nt * 16, kk), aI[nt], 0, 0, 0);
        }
    }
    // X@M1 hoisted: results not consumed until epilogue, so the matrix pipe
    // chews on it across the barriers + scan below
#pragma unroll
    for (int kh2 = 0; kh2 < 2; ++kh2) {
        const int kk = kh2 * 32;
#pragma unroll
        for (int tt = 0; tt < 4; ++tt)
            acc[tt] = __builtin_amdgcn_mfma_f32_16x16x32_f16(
                axk[kh2], MFRAG(MM1, tt * 16, kk), acc[tt], 0, 0, 0);
    }
    __builtin_amdgcn_s_setprio(0);
    __syncthreads();  // ALL waves' U/M1 fragment reads complete -> safe clobber

    // u write: column rotated by 16*wb (= 16*((cc>>4)&3), wave-uniform)
#pragma unroll
    for (int nt = 0; nt < 4; ++nt)
#pragma unroll
        for (int rg = 0; rg < 4; ++rg) {
            const int cc = band + qd * 4 + rg;
            const int ncol = ((nt * 16 + col) + wb * 16) & 63;
            *(_Float16*)(sm + uRo + cc * 136 + ncol * 2) = (_Float16)aR[nt][rg];
            *(_Float16*)(sm + uIo + cc * 136 + ncol * 2) = (_Float16)aI[nt][rg];
        }
    __syncthreads();  // u visible

    // ---- phase 2: 64-lane 3-step scan; lane owns (cg = lane>>4 chunk
    //      group, nn = lane&15 -> n = band+nn). Exclusive S in-place.
    //      u values are read ONCE into registers (aR/aI dead -> regs free);
    //      step 3 is write-only. Column rotation (16*cg) keeps each cg
    //      group on its own 8-bank set.
    {
        const int nn = lane & 15, cg = lane >> 4;
        const int n = band + nn;
        const int ncol = (n + cg * 16) & 63;          // rotation for this cg
        const int c0 = cg * 16;
        // W16 = ww^16, W32 = ww^32 (4-5 squarings)
        const float W2R = fmaf(swR, swR, -swI * swI), W2I = 2.0f * swR * swI;
        const float W4R = fmaf(W2R, W2R, -W2I * W2I), W4I = 2.0f * W2R * W2I;
        const float W8R = fmaf(W4R, W4R, -W4I * W4I), W8I = 2.0f * W4R * W4I;
        const float W16R = fmaf(W8R, W8R, -W8I * W8I), W16I = 2.0f * W8R * W8I;
        const float W32R = fmaf(W16R, W16R, -W16I * W16I),
                    W32I = 2.0f * W16R * W16I;
        // step 1: load u into registers + group total
        float uRv[16], uIv[16];
#pragma unroll
        for (int i = 0; i < 16; ++i) {
            uRv[i] = (float)*(const _Float16*)(sm + uRo + (c0 + i) * 136 + ncol * 2);
            uIv[i] = (float)*(const _Float16*)(sm + uIo + (c0 + i) * 136 + ncol * 2);
        }
        float tRv = 0.0f, tIv = 0.0f;
#pragma unroll
        for (int i = 0; i < 16; ++i) {
            const float nR = fmaf(swR, tRv, fmaf(-swI, tIv, uRv[i]));
            tIv = fmaf(swR, tIv, fmaf(swI, tRv, uIv[i]));
            tRv = nR;
        }
        // step 2: weighted KS across cg groups (within this wave)
        float GR = tRv, GI = tIv;
        float xR = __shfl_up(GR, 16), xI = __shfl_up(GI, 16);
        if (cg >= 1) {
            const float t2 = fmaf(W16R, xR, fmaf(-W16I, xI, GR));
            GI = fmaf(W16R, xI, fmaf(W16I, xR, GI));
            GR = t2;
        }
        xR = __shfl_up(GR, 32); xI = __shfl_up(GI, 32);
        if (cg >= 2) {
            const float t2 = fmaf(W32R, xR, fmaf(-W32I, xI, GR));
            GI = fmaf(W32R, xI, fmaf(W32I, xR, GI));
            GR = t2;
        }
        const float pR = __shfl_up(GR, 16), pI = __shfl_up(GI, 16);
        float sR = (cg == 0) ? 0.0f : pR;
        float sI = (cg == 0) ? 0.0f : pI;
        // step 3: exclusive write + advance, WRITE-ONLY (u from registers)
#pragma unroll
        for (int i = 0; i < 16; ++i) {
            const int c = c0 + i;
            *(_Float16*)(sm + uRo + c * 136 + ncol * 2) = (_Float16)sR;
            *(_Float16*)(sm + uIo + c * 136 + ncol * 2) = (_Float16)sI;
            const float nR = fmaf(swR, sR, fmaf(-swI, sI, uRv[i]));
            sI = fmaf(swR, sI, fmaf(swI, sR, uIv[i]));
            sR = nR;
        }
    }
    __syncthreads();  // S visible

    // ---- phase 3: acc += SR@PR^T + SI@PIneg^T (rotated unit index) ----
    __builtin_amdgcn_s_setprio(1);
#pragma unroll
    for (int kh2 = 0; kh2 < 2; ++kh2) {
        const int kk = kh2 * 32;
        const int ubase = ((kk + qd * 8) + wb * 16) & 63;   // rotation = 16*wb
        const f16x8 as = ufrag(sm, uRo + (band + col) * 136 + ubase * 2);
#pragma unroll
        for (int tt = 0; tt < 4; ++tt)
            acc[tt] = __builtin_amdgcn_mfma_f32_16x16x32_f16(
                as, MFRAG(MPR, tt * 16, kk), acc[tt], 0, 0, 0);
    }
#pragma unroll
    for (int kh2 = 0; kh2 < 2; ++kh2) {
        const int kk = kh2 * 32;
        const int ubase = ((kk + qd * 8) + wb * 16) & 63;
        const f16x8 az = ufrag(sm, uIo + (band + col) * 136 + ubase * 2);
#pragma unroll
        for (int tt = 0; tt < 4; ++tt)
            acc[tt] = __builtin_amdgcn_mfma_f32_16x16x32_f16(
                az, MFRAG(MPI, tt * 16, kk), acc[tt], 0, 0, 0);
    }
    __builtin_amdgcn_s_setprio(0);

    // ---- epilogue via LDS bounce (wave-local; reuses own S slice):
    // f32 staging rows 0..7 in S_R slice, rows 8..15 in S_I slice,
    // stride 272B. Read-back mapped to the axk lane assignment:
    // lane (col,qd), kh2 reads row=col, taus kh2*32+qd*8..+7 — the exact
    // elements this lane holds in axk[kh2] — fusing r = x*(1+D) + y with
    // ZERO extra global reads. ----
#pragma unroll
    for (int tt = 0; tt < 4; ++tt)
#pragma unroll
        for (int rg = 0; rg < 4; ++rg) {
            const int row = qd * 4 + rg;
            const int base = (row < 8) ? uRo + band * 136 + row * 272
                                       : uIo + band * 136 + (row - 8) * 272;
            *(float*)(sm + base + (tt * 16 + col) * 4) = acc[tt][rg];
        }
#pragma unroll
    for (int kh2 = 0; kh2 < 2; ++kh2) {
        const int tau0 = kh2 * 32 + qd * 8;
        const int base = (col < 8) ? uRo + band * 136 + col * 272
                                   : uIo + band * 136 + (col - 8) * 272;
        const float4 y0 = *(const float4*)(sm + base + tau0 * 4);
        const float4 y1 = *(const float4*)(sm + base + tau0 * 4 + 16);
        const f16x8 xv = axk[kh2];
        f16x8 o;
        o[0] = (_Float16)fmaf((float)xv[0], Dp1, y0.x);
        o[1] = (_Float16)fmaf((float)xv[1], Dp1, y0.y);
        o[2] = (_Float16)fmaf((float)xv[2], Dp1, y0.z);
        o[3] = (_Float16)fmaf((float)xv[3], Dp1, y0.w);
        o[4] = (_Float16)fmaf((float)xv[4], Dp1, y1.x);
        o[5] = (_Float16)fmaf((float)xv[5], Dp1, y1.y);
        o[6] = (_Float16)fmaf((float)xv[6], Dp1, y1.z);
        o[7] = (_Float16)fmaf((float)xv[7], Dp1, y1.w);
        // l = (band+col)*64 + tau0 -> lt2 = (band+col)*2 + kh2, li = qd*8
        const int lt2 = (band + col) * 2 + kh2;
        const int li = qd * 8;
        *(f16x8*)(rt + (((size_t)b * 128 + lt2) * 1024 + h) * 32 + li) = o;
    }
}

// ---------------------------------------------------------------------------
// K3: LayerNorm + transpose back from l-tiled rt [B][L/32][H][32] f16.
// Pass 1: fully-coalesced reads (1KB contiguous per wave), stage LDS tile
// [l][h] + 8 per-l register sums, shfl_xor(4..32) reduce. Pass 2: f16x4 LDS
// reads along h, normalize, 256B-contiguous float4 writes. 2 blocks/CU.
// ---------------------------------------------------------------------------
#define HPAD 1032
__global__ __launch_bounds__(512, 2) void k_ln(const _Float16* __restrict__ rt,
                                               float* __restrict__ out,
                                               const float* __restrict__ lnw,
                                               const float* __restrict__ lnb) {
    __shared__ _Float16 tile[32 * HPAD];          // [l][h], 66048B
    __shared__ float ps[8][32], pq[8][32];
    __shared__ float mm[32], rs[32];
    const int b  = blockIdx.y;
    const int lt = blockIdx.x;                    // 32-l tile index
    const int tid = threadIdx.x;
    const int lane = tid & 63, wvv = tid >> 6;
    const int oct = tid & 3;                      // li-octet: li = oct*8..+7
    const int hloc = tid >> 2;                    // 0..127

    const _Float16* base = rt + ((size_t)b * 128 + lt) * 1024 * 32;

    float s[8] = {}, q[8] = {};
#pragma unroll
    for (int p = 0; p < 8; ++p) {
        const int h = p * 128 + hloc;
        const f16x8 v = *(const f16x8*)(base + h * 32 + oct * 8);
#pragma unroll
        for (int j = 0; j < 8; ++j) {
            const float f = (float)v[j];
            tile[(oct * 8 + j) * HPAD + h] = v[j];
            s[j] += f;
            q[j] = fmaf(f, f, q[j]);
        }
    }
    // reduce across lanes sharing oct (stride 4): d = 4,8,16,32
#pragma unroll
    for (int d = 4; d <= 32; d <<= 1) {
#pragma unroll
        for (int j = 0; j < 8; ++j) {
            s[j] += __shfl_xor(s[j], d);
            q[j] += __shfl_xor(q[j], d);
        }
    }
    if ((lane >> 2) == 0) {   // lanes 0..3, one per oct
#pragma unroll
        for (int j = 0; j < 8; ++j) {
            ps[wvv][oct * 8 + j] = s[j];
            pq[wvv][oct * 8 + j] = q[j];
        }
    }
    __syncthreads();
    if (tid < 32) {
        float ss = 0.f, qq = 0.f;
#pragma unroll
        for (int w = 0; w < 8; ++w) { ss += ps[w][tid]; qq += pq[w][tid]; }
        const float mu  = ss * (1.0f / Hh);
        const float var = fmaf(-mu, mu, qq * (1.0f / Hh));
        mm[tid] = mu;
        rs[tid] = rsqrtf(var + LN_EPS);
    }
    __syncthreads();

    // pass 2: thread t -> l = t>>4 (0..31), hq0 = t&15
    const int l = tid >> 4, hq0 = tid & 15;
    const float mu = mm[l], rsg = rs[l];
    float* obase = out + ((size_t)(b * Lseq + lt * 32 + l)) * Hh;
#pragma unroll
    for (int p = 0; p < 16; ++p) {
        const int hh = (p * 16 + hq0) * 4;
        const f16x4 v = *(const f16x4*)(&tile[l * HPAD + hh]);
        const float4 w4 = *(const float4*)(lnw + hh);
        const float4 b4 = *(const float4*)(lnb + hh);
        float4 o;
        o.x = fmaf(((float)v[0] - mu) * rsg, w4.x, b4.x);
        o.y = fmaf(((float)v[1] - mu) * rsg, w4.y, b4.y);
        o.z = fmaf(((float)v[2] - mu) * rsg, w4.z, b4.z);
        o.w = fmaf(((float)v[3] - mu) * rsg, w4.w, b4.w);
        *(float4*)(obase + hh) = o;
    }
}

// ---------------------------------------------------------------------------
extern "C" void kernel_launch(void* const* d_in, const int* in_sizes, int n_in,
                              void* d_out, int out_size, void* d_ws, size_t ws_size,
                              hipStream_t stream) {
    const float* x     = (const float*)d_in[0];
    const float* logA  = (const float*)d_in[1];
    const float* Aim   = (const float*)d_in[2];
    const float* Cre   = (const float*)d_in[3];
    const float* Cim   = (const float*)d_in[4];
    const float* logdt = (const float*)d_in[5];
    const float* Dp    = (const float*)d_in[6];
    const float* lnw   = (const float*)d_in[7];
    const float* lnb   = (const float*)d_in[8];
    float* out = (float*)d_out;

    _Float16* xt = (_Float16*)d_ws;                        // 32 MiB f16 [B,H,L]
    _Float16* rt = xt + (size_t)Bb * Hh * Lseq;            // 32 MiB f16 tiled

    char* tb = (char*)d_out;                               // 7 x 256 KiB tables
    float* wwR  = (float*)(tb);
    float* wwI  = (float*)(tb + 262144);
    float* w1R  = (float*)(tb + 2 * 262144);
    float* w1I  = (float*)(tb + 3 * 262144);
    float* cRt  = (float*)(tb + 4 * 262144);
    float* cIt  = (float*)(tb + 5 * 262144);
    float* ktab = (float*)(tb + 6 * 262144);

    // precompute blocks (0..1023) overlap transpose blocks (1024..5119)
    k_pre_trans<<<dim3(Hh + (Hh / 64) * (Lseq / 64) * Bb), 256, 0, stream>>>(
        x, xt, logA, Aim, Cre, Cim, logdt, wwR, wwI, w1R, w1I, cRt, cIt, ktab);
    k_chunk<<<dim3(2, Hh), 512, 0, stream>>>(xt, rt, wwR, wwI,
                                             w1R, w1I, cRt, cIt, ktab, Dp);
    k_ln<<<dim3(Lseq / 32, Bb), 512, 0, stream>>>(rt, out, lnw, lnb);
}

// Round 17
// 174.254 us; speedup vs baseline: 1.0111x; 1.0111x over previous
//
#include <hip/hip_runtime.h>
#include <cstdint>

#define Bb 4
#define Lseq 4096
#define Hh 1024
#define Nst 64
constexpr float LN_EPS = 1e-5f;

typedef _Float16 f16x8 __attribute__((ext_vector_type(8)));
typedef _Float16 f16x4 __attribute__((ext_vector_type(4)));
typedef float f32x4v __attribute__((ext_vector_type(4)));

// XOR-swizzle within a 64x64 f16 matrix: elem e=(row*64+col) stored at
// e ^ ((row&7)<<3). ALL matrices (U, M1, P) are generated in-kernel in
// k_chunk directly at swizzled LDS offsets — no global mats buffer at all.
__device__ __forceinline__ void cmul(float& zR, float& zI, float bR, float bI) {
    const float tR = fmaf(zR, bR, -zI * bI);
    zI = fmaf(zR, bI, zI * bR);
    zR = tR;
}

// ---------------------------------------------------------------------------
// K0+K1 fused: precompute (blocks 0..1023) overlaps transpose (blocks 1024+).
// Precompute emits ONLY small tables: w1 = exp(dA), w64 (scan weight),
// Ct (cR/cI), K[0..63] per h.
// ---------------------------------------------------------------------------
__global__ __launch_bounds__(256) void k_pre_trans(
    const float* __restrict__ x, _Float16* __restrict__ xt,
    const float* __restrict__ logA, const float* __restrict__ Aim,
    const float* __restrict__ Cre, const float* __restrict__ Cim,
    const float* __restrict__ logdt,
    float* __restrict__ wwR, float* __restrict__ wwI,
    float* __restrict__ w1R, float* __restrict__ w1I,
    float* __restrict__ cRt, float* __restrict__ cIt,
    float* __restrict__ ktab) {
    __shared__ float tile[64 * 65];               // transpose path (16.6KB)
    __shared__ float sdAr[64], sdAi[64], scR[64], scI[64];
    const int tid = threadIdx.x;

    if (blockIdx.x < Hh) {
        // ---------------- precompute path (tables only) ----------------
        const int h = blockIdx.x;

        if (tid < 64) {
            const int n = tid, idx = h * 64 + n;
            const float ar = -__expf(logA[idx]), ai = Aim[idx];
            const float dt = __expf(logdt[h]);
            const float dAr = dt * ar, dAi = dt * ai;
            const float em = __expf(dAr);
            const float wr = em * __cosf(dAi), wi = em * __sinf(dAi);
            const float Er = wr - 1.0f, Ei = wi;
            const float cr = Cre[idx], ci = Cim[idx];
            const float nr = cr * Er - ci * Ei, ni = cr * Ei + ci * Er;
            const float invd = 1.0f / (ar * ar + ai * ai);
            const float CtR = (nr * ar + ni * ai) * invd;
            const float CtI = (ni * ar - nr * ai) * invd;
            sdAr[n] = dAr; sdAi[n] = dAi;
            scR[n] = 2.0f * CtR; scI[n] = 2.0f * CtI;
            w1R[idx] = wr;  w1I[idx] = wi;        // w = exp(dA)
            cRt[idx] = 2.0f * CtR; cIt[idx] = 2.0f * CtI;
            const float e64 = __expf(dAr * 64.0f), a64 = dAi * 64.0f;
            wwR[idx] = e64 * __cosf(a64);         // w^64 (scan weight)
            wwI[idx] = e64 * __sinf(a64);
        }
        __syncthreads();

        // K[tau] -> global ktab: tau = tid>>2, each of 4 lanes sums 16 n's,
        // then shfl_xor(1,2) reduce within the aligned 4-lane group.
        {
            const int tau = tid >> 2, ns0 = (tid & 3) * 16;
            const float ftau = (float)tau;
            float sum = 0.0f;
#pragma unroll
            for (int j = 0; j < 16; ++j) {
                const int n = ns0 + j;
                const float ee = __expf(sdAr[n] * ftau), ang = sdAi[n] * ftau;
                sum += ee * (scR[n] * __cosf(ang) - scI[n] * __sinf(ang));
            }
            sum += __shfl_xor(sum, 1);
            sum += __shfl_xor(sum, 2);
            if ((tid & 3) == 0) ktab[h * 64 + tau] = sum;
        }
    } else {
        // ---------------- transpose path (f32 in, f16 out) ----------------
        const int tb = blockIdx.x - Hh;
        const int h0 = (tb & 15) * 64;
        const int l0 = ((tb >> 4) & 63) * 64;
        const int b  = tb >> 10;
        const int c = tid & 15, r = tid >> 4;

        const float* src = x + ((size_t)(b * Lseq + l0 + r)) * Hh + h0 + 4 * c;
#pragma unroll
        for (int it = 0; it < 4; ++it) {
            const float4 v = *(const float4*)(src + (size_t)it * 16 * Hh);
            const int l = it * 16 + r;
            tile[(4 * c + 0) * 65 + l] = v.x;
            tile[(4 * c + 1) * 65 + l] = v.y;
            tile[(4 * c + 2) * 65 + l] = v.z;
            tile[(4 * c + 3) * 65 + l] = v.w;
        }
        __syncthreads();
        // store pass: 8 l-octets x 32 h-rows -> 2x 16B f16x8 stores/thread
        const int c8 = tid & 7, r32 = tid >> 3;
        _Float16* dst = xt + ((size_t)(b * Hh + h0 + r32)) * Lseq + l0 + 8 * c8;
#pragma unroll
        for (int it = 0; it < 2; ++it) {
            const float* trow = tile + (it * 32 + r32) * 65 + 8 * c8;
            f16x8 o;
#pragma unroll
            for (int j = 0; j < 8; ++j) o[j] = (_Float16)trow[j];
            *(f16x8*)(dst + (size_t)it * 32 * Lseq) = o;
        }
    }
}

// ---------------------------------------------------------------------------
// K2: chunked block-scan via MFMA. 512 threads / 2 batches per block,
// grid (2, Hh), 3 blocks/CU (51200B LDS overlay). R15 configuration — the
// verified optimum: U/M1/P generated in-kernel into swizzled LDS, LDS
// liveness overlay (u/S over U/M1), rotated-column scan (bank-conflict-
// free), axk-register epilogue, no spills at the 6-wave register budget.
// (R16's register-u scan variant spilled: WRITE +8MB — reverted.)
// ---------------------------------------------------------------------------
#define MR0 0        // U_re   f16 [64][64] stride 128B, XOR-swizzled (phase 1)
#define MI0 8192     // U_im   (phase 1)
#define MM1 16384    // M1     (phase 1)
#define USB 0        // u/S: 2 x { S_R [64][68], S_I [64][68] } stride 136B
                     //   overlaps U/M1 after the post-phase-1 barrier
#define MPR 34816    // P_re   (generated, disjoint)
#define MPI 43008    // P_im_neg

// row0 is a multiple of 16 at every use, so (row0+col)&7 == col&7
#define MFRAG(base, row0, kk) \
    (*(const f16x8*)(sm + (((base) + ((row0) + col) * 128 + ((kk) + qd * 8) * 2) ^ ((col & 7) << 4))))

static __device__ __forceinline__ f16x8 ufrag(const unsigned char* sm, int off) {
    union { f16x8 v; f16x4 h[2]; } u;
    u.h[0] = *(const f16x4*)(sm + off);      // 8B aligned
    u.h[1] = *(const f16x4*)(sm + off + 8);
    return u.v;
}

__global__ __launch_bounds__(512, 6) void k_chunk(
    const _Float16* __restrict__ xt, _Float16* __restrict__ rt,
    const float* __restrict__ wwR, const float* __restrict__ wwI,
    const float* __restrict__ w1R, const float* __restrict__ w1I,
    const float* __restrict__ cRt, const float* __restrict__ cIt,
    const float* __restrict__ ktab, const float* __restrict__ Dp) {
    __shared__ __align__(16) unsigned char sm[51200];

    const int tid = threadIdx.x, lane = tid & 63, wv = tid >> 6;
    const int grp = wv >> 2;          // 0..1: which batch of this block's pair
    const int wb  = wv & 3;           // row-band wave 0..3
    const int h = blockIdx.y;
    const int b = blockIdx.x * 2 + grp;   // batch 0..3
    const int col = lane & 15, qd = lane >> 4;
    const int band = wb * 16;
    const int uRo = USB + grp * 17408;
    const int uIo = uRo + 8704;

    const float Dp1 = 1.0f + Dp[h];
    const _Float16* xr = xt + ((size_t)b * Hh + h) * Lseq;

    // ---- phase-1 fragment loads (latency hides under U/M1/P gen) ----
    f16x8 axk[2];
#pragma unroll
    for (int kh2 = 0; kh2 < 2; ++kh2)
        axk[kh2] = *(const f16x8*)(xr + (band + col) * 64 + kh2 * 32 + qd * 8);

    // scan weight ww = w^64 for this lane's n = band + (lane&15); all lanes
    const float swR = wwR[h * 64 + band + (lane & 15)];
    const float swI = wwI[h * 64 + band + (lane & 15)];

    // ---- generate U (w^p geometric rows) into swizzled LDS ----
    {
        const int n = tid >> 3, oct = tid & 7;
        const float wR = w1R[h * 64 + n], wI = w1I[h * 64 + n];
        const float w2R = fmaf(wR, wR, -wI * wI),     w2I = 2.0f * wR * wI;
        const float w4R = fmaf(w2R, w2R, -w2I * w2I), w4I = 2.0f * w2R * w2I;
        const float w8R = fmaf(w4R, w4R, -w4I * w4I), w8I = 2.0f * w4R * w4I;
        const int k = 7 - oct;                        // z = (w^8)^k
        float zR = 1.0f, zI = 0.0f;
        if (k & 1) cmul(zR, zI, w8R, w8I);
        const float w16R = fmaf(w8R, w8R, -w8I * w8I), w16I = 2.0f * w8R * w8I;
        if (k & 2) cmul(zR, zI, w16R, w16I);
        const float w32R = fmaf(w16R, w16R, -w16I * w16I),
                    w32I = 2.0f * w16R * w16I;
        if (k & 4) cmul(zR, zI, w32R, w32I);
        // octet elems: v[j] = w^(63-8*oct-j); j=7 -> z, then multiply up
        f16x8 ur, ui;
        ur[7] = (_Float16)zR; ui[7] = (_Float16)zI;
#pragma unroll
        for (int j = 6; j >= 0; --j) {
            cmul(zR, zI, wR, wI);
            ur[j] = (_Float16)zR; ui[j] = (_Float16)zI;
        }
        const int sb = n * 128 + ((oct ^ (n & 7)) << 4);
        *(f16x8*)(sm + MR0 + sb) = ur;
        *(f16x8*)(sm + MI0 + sb) = ui;
    }

    // ---- generate M1 (tril Toeplitz of K) into swizzled LDS ----
    {
        const int t = tid >> 3, oct = tid & 7;
        f16x8 m1;
#pragma unroll
        for (int i = 0; i < 8; ++i) {
            const int j = oct * 8 + i;
            float v = 0.0f;
            if (j <= t) v = ktab[h * 64 + (t - j)];
            m1[i] = (_Float16)v;
        }
        const int sb = t * 128 + ((oct ^ (t & 7)) << 4);
        *(f16x8*)(sm + MM1 + sb) = m1;
    }

    // ---- generate P (Ct * w^(t+1), geometric in t) into swizzled LDS ----
    {
        const int n = tid & 63, k = tid >> 6;
        const float wR = w1R[h * 64 + n], wI = w1I[h * 64 + n];
        const float w2R = fmaf(wR, wR, -wI * wI),     w2I = 2.0f * wR * wI;
        const float w4R = fmaf(w2R, w2R, -w2I * w2I), w4I = 2.0f * w2R * w2I;
        const float w8R = fmaf(w4R, w4R, -w4I * w4I), w8I = 2.0f * w4R * w4I;
        float zR = 1.0f, zI = 0.0f;                   // w^(8k)
        if (k & 1) cmul(zR, zI, w8R, w8I);
        const float w16R = fmaf(w8R, w8R, -w8I * w8I), w16I = 2.0f * w8R * w8I;
        if (k & 2) cmul(zR, zI, w16R, w16I);
        const float w32R = fmaf(w16R, w16R, -w16I * w16I),
                    w32I = 2.0f * w16R * w16I;
        if (k & 4) cmul(zR, zI, w32R, w32I);
        float pR = cRt[h * 64 + n], pI = cIt[h * 64 + n];   // Ct
        cmul(pR, pI, zR, zI);                         // Ct * w^(8k)
        cmul(pR, pI, wR, wI);                         // Ct * w^(8k+1)
#pragma unroll
        for (int j = 0; j < 8; ++j) {
            const int t = k * 8 + j;
            const int off = t * 128 + ((n * 2) ^ (j << 4));
            *(_Float16*)(sm + MPR + off) = (_Float16)pR;
            *(_Float16*)(sm + MPI + off) = (_Float16)(-pI);
            cmul(pR, pI, wR, wI);
        }
    }
    __syncthreads();  // U/M1/P in LDS + x loads ready

    // ---- phase 1: u = X @ U^T (complex) + hoisted X@M1 ----
    f32x4v aR[4] = {}, aI[4] = {};
    f32x4v acc[4] = {};
    __builtin_amdgcn_s_setprio(1);
#pragma unroll
    for (int kh2 = 0; kh2 < 2; ++kh2) {
        const int kk = kh2 * 32;
#pragma unroll
        for (int nt = 0; nt < 4; ++nt) {
            aR[nt] = __builtin_amdgcn_mfma_f32_16x16x32_f16(
                axk[kh2], MFRAG(MR0, nt * 16, kk), aR[nt], 0, 0, 0);
            aI[nt] = __builtin_amdgcn_mfma_f32_16x16x32_f16(
                axk[kh2], MFRAG(MI0, nt * 16, kk), aI[nt], 0, 0, 0);
        }
    }
    // X@M1 hoisted: results not consumed until epilogue, so the matrix pipe
    // chews on it across the barriers + scan below
#pragma unroll
    for (int kh2 = 0; kh2 < 2; ++kh2) {
        const int kk = kh2 * 32;
#pragma unroll
        for (int tt = 0; tt < 4; ++tt)
            acc[tt] = __builtin_amdgcn_mfma_f32_16x16x32_f16(
                axk[kh2], MFRAG(MM1, tt * 16, kk), acc[tt], 0, 0, 0);
    }
    __builtin_amdgcn_s_setprio(0);
    __syncthreads();  // ALL waves' U/M1 fragment reads complete -> safe clobber

    // u write: column rotated by 16*wb (= 16*((cc>>4)&3), wave-uniform)
#pragma unroll
    for (int nt = 0; nt < 4; ++nt)
#pragma unroll
        for (int rg = 0; rg < 4; ++rg) {
            const int cc = band + qd * 4 + rg;
            const int ncol = ((nt * 16 + col) + wb * 16) & 63;
            *(_Float16*)(sm + uRo + cc * 136 + ncol * 2) = (_Float16)aR[nt][rg];
            *(_Float16*)(sm + uIo + cc * 136 + ncol * 2) = (_Float16)aI[nt][rg];
        }
    __syncthreads();  // u visible

    // ---- phase 2: 64-lane 3-step scan; lane owns (cg = lane>>4 chunk
    //      group, nn = lane&15 -> n = band+nn). Exclusive S in-place.
    //      Column rotation (16*cg) puts each cg group on its own 8-bank set.
    {
        const int nn = lane & 15, cg = lane >> 4;
        const int n = band + nn;
        const int ncol = (n + cg * 16) & 63;          // rotation for this cg
        const int c0 = cg * 16;
        // W16 = ww^16, W32 = ww^32 (4-5 squarings)
        const float W2R = fmaf(swR, swR, -swI * swI), W2I = 2.0f * swR * swI;
        const float W4R = fmaf(W2R, W2R, -W2I * W2I), W4I = 2.0f * W2R * W2I;
        const float W8R = fmaf(W4R, W4R, -W4I * W4I), W8I = 2.0f * W4R * W4I;
        const float W16R = fmaf(W8R, W8R, -W8I * W8I), W16I = 2.0f * W8R * W8I;
        const float W32R = fmaf(W16R, W16R, -W16I * W16I),
                    W32I = 2.0f * W16R * W16I;
        // step 1: group total (read-only)
        float tRv = 0.0f, tIv = 0.0f;
#pragma unroll
        for (int i = 0; i < 16; ++i) {
            const int c = c0 + i;
            const float uRv = (float)*(const _Float16*)(sm + uRo + c * 136 + ncol * 2);
            const float uIv = (float)*(const _Float16*)(sm + uIo + c * 136 + ncol * 2);
            const float nR = fmaf(swR, tRv, fmaf(-swI, tIv, uRv));
            tIv = fmaf(swR, tIv, fmaf(swI, tRv, uIv));
            tRv = nR;
        }
        // step 2: weighted KS across cg groups (within this wave)
        float GR = tRv, GI = tIv;
        float xR = __shfl_up(GR, 16), xI = __shfl_up(GI, 16);
        if (cg >= 1) {
            const float t2 = fmaf(W16R, xR, fmaf(-W16I, xI, GR));
            GI = fmaf(W16R, xI, fmaf(W16I, xR, GI));
            GR = t2;
        }
        xR = __shfl_up(GR, 32); xI = __shfl_up(GI, 32);
        if (cg >= 2) {
            const float t2 = fmaf(W32R, xR, fmaf(-W32I, xI, GR));
            GI = fmaf(W32R, xI, fmaf(W32I, xR, GI));
            GR = t2;
        }
        const float pR = __shfl_up(GR, 16), pI = __shfl_up(GI, 16);
        float sR = (cg == 0) ? 0.0f : pR;
        float sI = (cg == 0) ? 0.0f : pI;
        // step 3: exclusive write + advance (each element owned by this lane)
#pragma unroll
        for (int i = 0; i < 16; ++i) {
            const int c = c0 + i;
            _Float16* qR = (_Float16*)(sm + uRo + c * 136 + ncol * 2);
            _Float16* qI = (_Float16*)(sm + uIo + c * 136 + ncol * 2);
            const float uRv = (float)*qR;
            const float uIv = (float)*qI;
            *qR = (_Float16)sR;
            *qI = (_Float16)sI;
            const float nR = fmaf(swR, sR, fmaf(-swI, sI, uRv));
            sI = fmaf(swR, sI, fmaf(swI, sR, uIv));
            sR = nR;
        }
    }
    __syncthreads();  // S visible

    // ---- phase 3: acc += SR@PR^T + SI@PIneg^T (rotated unit index) ----
    __builtin_amdgcn_s_setprio(1);
#pragma unroll
    for (int kh2 = 0; kh2 < 2; ++kh2) {
        const int kk = kh2 * 32;
        const int ubase = ((kk + qd * 8) + wb * 16) & 63;   // rotation = 16*wb
        const f16x8 as = ufrag(sm, uRo + (band + col) * 136 + ubase * 2);
#pragma unroll
        for (int tt = 0; tt < 4; ++tt)
            acc[tt] = __builtin_amdgcn_mfma_f32_16x16x32_f16(
                as, MFRAG(MPR, tt * 16, kk), acc[tt], 0, 0, 0);
    }
#pragma unroll
    for (int kh2 = 0; kh2 < 2; ++kh2) {
        const int kk = kh2 * 32;
        const int ubase = ((kk + qd * 8) + wb * 16) & 63;
        const f16x8 az = ufrag(sm, uIo + (band + col) * 136 + ubase * 2);
#pragma unroll
        for (int tt = 0; tt < 4; ++tt)
            acc[tt] = __builtin_amdgcn_mfma_f32_16x16x32_f16(
                az, MFRAG(MPI, tt * 16, kk), acc[tt], 0, 0, 0);
    }
    __builtin_amdgcn_s_setprio(0);

    // ---- epilogue via LDS bounce (wave-local; reuses own S slice):
    // f32 staging rows 0..7 in S_R slice, rows 8..15 in S_I slice,
    // stride 272B. Read-back mapped to the axk lane assignment:
    // lane (col,qd), kh2 reads row=col, taus kh2*32+qd*8..+7 — the exact
    // elements this lane holds in axk[kh2] — fusing r = x*(1+D) + y with
    // ZERO extra global reads. ----
#pragma unroll
    for (int tt = 0; tt < 4; ++tt)
#pragma unroll
        for (int rg = 0; rg < 4; ++rg) {
            const int row = qd * 4 + rg;
            const int base = (row < 8) ? uRo + band * 136 + row * 272
                                       : uIo + band * 136 + (row - 8) * 272;
            *(float*)(sm + base + (tt * 16 + col) * 4) = acc[tt][rg];
        }
#pragma unroll
    for (int kh2 = 0; kh2 < 2; ++kh2) {
        const int tau0 = kh2 * 32 + qd * 8;
        const int base = (col < 8) ? uRo + band * 136 + col * 272
                                   : uIo + band * 136 + (col - 8) * 272;
        const float4 y0 = *(const float4*)(sm + base + tau0 * 4);
        const float4 y1 = *(const float4*)(sm + base + tau0 * 4 + 16);
        const f16x8 xv = axk[kh2];
        f16x8 o;
        o[0] = (_Float16)fmaf((float)xv[0], Dp1, y0.x);
        o[1] = (_Float16)fmaf((float)xv[1], Dp1, y0.y);
        o[2] = (_Float16)fmaf((float)xv[2], Dp1, y0.z);
        o[3] = (_Float16)fmaf((float)xv[3], Dp1, y0.w);
        o[4] = (_Float16)fmaf((float)xv[4], Dp1, y1.x);
        o[5] = (_Float16)fmaf((float)xv[5], Dp1, y1.y);
        o[6] = (_Float16)fmaf((float)xv[6], Dp1, y1.z);
        o[7] = (_Float16)fmaf((float)xv[7], Dp1, y1.w);
        // l = (band+col)*64 + tau0 -> lt2 = (band+col)*2 + kh2, li = qd*8
        const int lt2 = (band + col) * 2 + kh2;
        const int li = qd * 8;
        *(f16x8*)(rt + (((size_t)b * 128 + lt2) * 1024 + h) * 32 + li) = o;
    }
}

// ---------------------------------------------------------------------------
// K3: LayerNorm + transpose back from l-tiled rt [B][L/32][H][32] f16.
// Pass 1: fully-coalesced reads (1KB contiguous per wave), stage LDS tile
// [l][h] + 8 per-l register sums, shfl_xor(4..32) reduce. Pass 2: f16x4 LDS
// reads along h, normalize, 256B-contiguous float4 writes. 2 blocks/CU.
// ---------------------------------------------------------------------------
#define HPAD 1032
__global__ __launch_bounds__(512, 2) void k_ln(const _Float16* __restrict__ rt,
                                               float* __restrict__ out,
                                               const float* __restrict__ lnw,
                                               const float* __restrict__ lnb) {
    __shared__ _Float16 tile[32 * HPAD];          // [l][h], 66048B
    __shared__ float ps[8][32], pq[8][32];
    __shared__ float mm[32], rs[32];
    const int b  = blockIdx.y;
    const int lt = blockIdx.x;                    // 32-l tile index
    const int tid = threadIdx.x;
    const int lane = tid & 63, wvv = tid >> 6;
    const int oct = tid & 3;                      // li-octet: li = oct*8..+7
    const int hloc = tid >> 2;                    // 0..127

    const _Float16* base = rt + ((size_t)b * 128 + lt) * 1024 * 32;

    float s[8] = {}, q[8] = {};
#pragma unroll
    for (int p = 0; p < 8; ++p) {
        const int h = p * 128 + hloc;
        const f16x8 v = *(const f16x8*)(base + h * 32 + oct * 8);
#pragma unroll
        for (int j = 0; j < 8; ++j) {
            const float f = (float)v[j];
            tile[(oct * 8 + j) * HPAD + h] = v[j];
            s[j] += f;
            q[j] = fmaf(f, f, q[j]);
        }
    }
    // reduce across lanes sharing oct (stride 4): d = 4,8,16,32
#pragma unroll
    for (int d = 4; d <= 32; d <<= 1) {
#pragma unroll
        for (int j = 0; j < 8; ++j) {
            s[j] += __shfl_xor(s[j], d);
            q[j] += __shfl_xor(q[j], d);
        }
    }
    if ((lane >> 2) == 0) {   // lanes 0..3, one per oct
#pragma unroll
        for (int j = 0; j < 8; ++j) {
            ps[wvv][oct * 8 + j] = s[j];
            pq[wvv][oct * 8 + j] = q[j];
        }
    }
    __syncthreads();
    if (tid < 32) {
        float ss = 0.f, qq = 0.f;
#pragma unroll
        for (int w = 0; w < 8; ++w) { ss += ps[w][tid]; qq += pq[w][tid]; }
        const float mu  = ss * (1.0f / Hh);
        const float var = fmaf(-mu, mu, qq * (1.0f / Hh));
        mm[tid] = mu;
        rs[tid] = rsqrtf(var + LN_EPS);
    }
    __syncthreads();

    // pass 2: thread t -> l = t>>4 (0..31), hq0 = t&15
    const int l = tid >> 4, hq0 = tid & 15;
    const float mu = mm[l], rsg = rs[l];
    float* obase = out + ((size_t)(b * Lseq + lt * 32 + l)) * Hh;
#pragma unroll
    for (int p = 0; p < 16; ++p) {
        const int hh = (p * 16 + hq0) * 4;
        const f16x4 v = *(const f16x4*)(&tile[l * HPAD + hh]);
        const float4 w4 = *(const float4*)(lnw + hh);
        const float4 b4 = *(const float4*)(lnb + hh);
        float4 o;
        o.x = fmaf(((float)v[0] - mu) * rsg, w4.x, b4.x);
        o.y = fmaf(((float)v[1] - mu) * rsg, w4.y, b4.y);
        o.z = fmaf(((float)v[2] - mu) * rsg, w4.z, b4.z);
        o.w = fmaf(((float)v[3] - mu) * rsg, w4.w, b4.w);
        *(float4*)(obase + hh) = o;
    }
}

// ---------------------------------------------------------------------------
extern "C" void kernel_launch(void* const* d_in, const int* in_sizes, int n_in,
                              void* d_out, int out_size, void* d_ws, size_t ws_size,
                              hipStream_t stream) {
    const float* x     = (const float*)d_in[0];
    const float* logA  = (const float*)d_in[1];
    const float* Aim   = (const float*)d_in[2];
    const float* Cre   = (const float*)d_in[3];
    const float* Cim   = (const float*)d_in[4];
    const float* logdt = (const float*)d_in[5];
    const float* Dp    = (const float*)d_in[6];
    const float* lnw   = (const float*)d_in[7];
    const float* lnb   = (const float*)d_in[8];
    float* out = (float*)d_out;

    _Float16* xt = (_Float16*)d_ws;                        // 32 MiB f16 [B,H,L]
    _Float16* rt = xt + (size_t)Bb * Hh * Lseq;            // 32 MiB f16 tiled

    char* tb = (char*)d_out;                               // 7 x 256 KiB tables
    float* wwR  = (float*)(tb);
    float* wwI  = (float*)(tb + 262144);
    float* w1R  = (float*)(tb + 2 * 262144);
    float* w1I  = (float*)(tb + 3 * 262144);
    float* cRt  = (float*)(tb + 4 * 262144);
    float* cIt  = (float*)(tb + 5 * 262144);
    float* ktab = (float*)(tb + 6 * 262144);

    // precompute blocks (0..1023) overlap transpose blocks (1024..5119)
    k_pre_trans<<<dim3(Hh + (Hh / 64) * (Lseq / 64) * Bb), 256, 0, stream>>>(
        x, xt, logA, Aim, Cre, Cim, logdt, wwR, wwI, w1R, w1I, cRt, cIt, ktab);
    k_chunk<<<dim3(2, Hh), 512, 0, stream>>>(xt, rt, wwR, wwI,
                                             w1R, w1I, cRt, cIt, ktab, Dp);
    k_ln<<<dim3(Lseq / 32, Bb), 512, 0, stream>>>(rt, out, lnw, lnb);
}